// Round 10
// baseline (19413.414 us; speedup 1.0000x reference)
//
#include <hip/hip_runtime.h>

#define Bsz 4096
#define Lsz 128
#define NI  127
#define SD  32
#define AD  8
#define LAT 64
#define HID 128
#define BT  16
#define THR 512

typedef float f32x2 __attribute__((ext_vector_type(2)));
typedef float f32x4 __attribute__((ext_vector_type(4)));

// ---------------- W2 repack ----------------
// W2 [128][64][9] -> W2p8 [j][l][8] (channels 1..8) + W2c0 [j][l] (channel 0)
__global__ __launch_bounds__(256) void repack_w2(const float* __restrict__ W2,
                                                 float* __restrict__ W2p8,
                                                 float* __restrict__ W2c0){
  int idx = blockIdx.x*256 + threadIdx.x;
  if (idx < HID*LAT*8){
    int x = idx & 7; int jl = idx >> 3; int l = jl & 63; int j = jl >> 6;
    W2p8[idx] = W2[(j*LAT + l)*9 + x + 1];
  } else if (idx < HID*LAT*9){
    int jl = idx - HID*LAT*8;
    W2c0[jl] = W2[(size_t)jl*9];
  }
}

// ---------------- Natural cubic spline: channels 1..8 (t-channel exactly linear) ----------------
__global__ __launch_bounds__(256) void spline_kernel(const float* __restrict__ a,
                                                     float* __restrict__ m_ws){
  __shared__ float cp_s[126];
  if (threadIdx.x == 0){
    float c = 0.25f; cp_s[0] = c;
    for (int i=1;i<126;i++){ c = 1.0f/(4.0f - c); cp_s[i] = c; }
  }
  __syncthreads();
  int tid = blockIdx.x*256 + threadIdx.x;   // tid = b*8 + c8
  int b = tid >> 3, c8 = tid & 7;
  float dp[126];
  const float* ab = a + (size_t)b*Lsz*AD + c8;
  float x0 = ab[0];
  float x1 = ab[AD];
  for (int i=0;i<126;i++){
    float x2 = ab[(size_t)(i+2)*AD];
    float rhs = 6.0f*(x2 - 2.0f*x1 + x0);
    dp[i] = (i==0)? rhs*0.25f : (rhs - dp[i-1])*cp_s[i];
    x0 = x1; x1 = x2;
  }
  m_ws[tid] = 0.0f;
  m_ws[((size_t)127*Bsz)*8 + tid] = 0.0f;
  float mn = 0.0f;
  for (int k=125;k>=0;k--){
    mn = dp[k] - cp_s[k]*mn;
    m_ws[((size_t)(k+1)*Bsz)*8 + tid] = mn;
  }
}

// ---- cross-lane helpers (32-bit) ----
#define DPP_XOR1(v) __int_as_float(__builtin_amdgcn_mov_dpp(__float_as_int(v), 0xB1, 0xF, 0xF, true))
#define DPP_XOR2(v) __int_as_float(__builtin_amdgcn_mov_dpp(__float_as_int(v), 0x4E, 0xF, 0xF, true))
#define SWZ_XOR4(v) __int_as_float(__builtin_amdgcn_ds_swizzle(__float_as_int(v), 0x101F))

// ---- packed fp32 ops (VOP3P). BCLO/BCHI broadcast src0's lo/hi half to both result halves ----
#define PK_MUL_BCLO(d, w, x) asm("v_pk_mul_f32 %0, %1, %2 op_sel:[0,0] op_sel_hi:[0,1]" : "=v"(d) : "v"(w), "v"(x))
#define PK_MUL_BCHI(d, w, x) asm("v_pk_mul_f32 %0, %1, %2 op_sel:[1,0] op_sel_hi:[1,1]" : "=v"(d) : "v"(w), "v"(x))
#define PK_FMA_BCLO(acc, w, x) asm("v_pk_fma_f32 %0, %1, %2, %0 op_sel:[0,0,0] op_sel_hi:[0,1,1]" : "+v"(acc) : "v"(w), "v"(x))
#define PK_FMA_BCHI(acc, w, x) asm("v_pk_fma_f32 %0, %1, %2, %0 op_sel:[1,0,0] op_sel_hi:[1,1,1]" : "+v"(acc) : "v"(w), "v"(x))
#define PK_FMA(acc, a, b)      asm("v_pk_fma_f32 %0, %1, %2, %0" : "+v"(acc) : "v"(a), "v"(b))
#define PK_ADD(d, a, b)        asm("v_pk_add_f32 %0, %1, %2" : "=v"(d) : "v"(a), "v"(b))

#define LO2(v4) __builtin_shufflevector(v4, v4, 0, 1)
#define HI2(v4) __builtin_shufflevector(v4, v4, 2, 3)

// ---------------- Persistent RK4 integrator: AGPR-resident W2, chunked AGPR->VGPR staging ----------------
__attribute__((amdgpu_waves_per_eu(2,2)))
__global__ __launch_bounds__(THR) void cde_integrate(
    const float* __restrict__ s, const float* __restrict__ a, const float* __restrict__ t,
    const float* __restrict__ encW, const float* __restrict__ encb,
    const float* __restrict__ W1, const float* __restrict__ b1,
    const float* __restrict__ b2, const float* __restrict__ decW, const float* __restrict__ decb,
    const float* __restrict__ W2p8, const float* __restrict__ W2c0, const float* __restrict__ m_ws,
    float* __restrict__ out)
{
  __shared__ float W1t[HID][LAT+4];   // [j][k], row 68
  __shared__ float hp[8][292];        // [b-pair][jblock*36 + slot*4 + {e0,o0,e1,o1}]
  __shared__ float zp[8][132];        // [b-pair][l*2 + c]
  __shared__ float dXp[5][8][20];     // [u][b-pair][x8*2 + c]
  __shared__ float dWs[LAT][SD];
  __shared__ float dbs[SD];

  const int tid = threadIdx.x;
  const int b0 = blockIdx.x * BT;
  const int ol = tid >> 3;   // 0..63 : latent l (GEMM2/RK4), j-pair (GEMM1)
  const int jg = tid & 7;    // 0..7  : j-group (GEMM2), b-pair (GEMM1/RK4)

  // ---- LDS weight staging ----
  for (int i=tid;i<HID*LAT;i+=THR){ int j = i & (HID-1); int k = i >> 7; W1t[j][k] = W1[k*HID+j]; }
  for (int i=tid;i<LAT*SD;i+=THR)  ((float*)dWs)[i] = decW[i];
  if (tid < SD) dbs[tid] = decb[tid];

  // ---- W2 -> AGPRs as channel pairs; j set = jg*16..+15 at column ol ----
  f32x2 wpk[16][4]; f32x2 wc0pk[8];
  {
    #pragma unroll
    for (int jj=0;jj<16;jj++){
      const f32x2* p2 = (const f32x2*)&W2p8[((size_t)(jg*16+jj)*LAT + ol)*8];
      wpk[jj][0]=p2[0]; wpk[jj][1]=p2[1]; wpk[jj][2]=p2[2]; wpk[jj][3]=p2[3];
    }
    #pragma unroll
    for (int q=0;q<8;q++){
      wc0pk[q].x = W2c0[(jg*16+2*q)*LAT + ol];
      wc0pk[q].y = W2c0[(jg*16+2*q+1)*LAT + ol];
    }
    // pin the persistent copies into AGPRs (VALU can't source them; we stage per chunk)
    #pragma unroll
    for (int jj=0;jj<16;jj++){
      asm volatile("" : "+a"(wpk[jj][0]), "+a"(wpk[jj][1]), "+a"(wpk[jj][2]), "+a"(wpk[jj][3]));
    }
    asm volatile("" : "+a"(wc0pk[0]), "+a"(wc0pk[1]), "+a"(wc0pk[2]), "+a"(wc0pk[3]),
                      "+a"(wc0pk[4]), "+a"(wc0pk[5]), "+a"(wc0pk[6]), "+a"(wc0pk[7]));
  }
  f32x2 b2p[4]; f32x2 b2c0v; f32x2 b1pair; f32x2 one11; one11.x = 1.f; one11.y = 1.f;
  {
    const float* bp = b2 + ol*9;
    b2c0v.x = bp[0]; b2c0v.y = 0.f;
    b2p[0].x = bp[1]; b2p[0].y = bp[2];
    b2p[1].x = bp[3]; b2p[1].y = bp[4];
    b2p[2].x = bp[5]; b2p[2].y = bp[6];
    b2p[3].x = bp[7]; b2p[3].y = bp[8];
    b1pair.x = b1[2*ol]; b1pair.y = b1[2*ol+1];
  }

  // ---- encode z0 ----
  {
    const int bb8 = tid >> 6;        // 0..7
    const int li = tid & 63;
    #pragma unroll
    for (int h=0; h<2; h++){
      const int b = bb8 + 8*h;
      const float* sb = s + (size_t)(b0+b)*Lsz*SD;
      const float* ab = a + (size_t)(b0+b)*Lsz*AD;
      const float tv = t[(size_t)(b0+b)*Lsz];
      float acc = encb[li];
      #pragma unroll
      for (int k=0;k<SD;k++) acc = fmaf(sb[k], encW[k*LAT+li], acc);
      #pragma unroll
      for (int k=0;k<AD;k++) acc = fmaf(ab[k], encW[(SD+k)*LAT+li], acc);
      acc = fmaf(tv, encW[(SD+AD)*LAT+li], acc);
      zp[b>>1][li*2 + (b&1)] = acc;
    }
  }
  __syncthreads();

  // ---- decode out[:,0,:] ----
  {
    const int bb = tid >> 5; const int o = tid & 31; const int c = bb & 1;
    const float* zrow = &zp[bb>>1][0];
    float acc = dbs[o];
    #pragma unroll 16
    for (int k=0;k<LAT;k++) acc = fmaf(zrow[2*k+c], dWs[k][o], acc);
    out[((size_t)(b0+bb)*Lsz + 0)*SD + o] = acc;
  }

  // ---- RK4 packed state: thread owns l=ol, b-pair jg ----
  float zb0, zb1, ka0 = 0.f, ka1 = 0.f;
  { f32x2 zr = *(const f32x2*)&zp[jg][2*ol]; zb0 = zr.x; zb1 = zr.y; }

  #pragma unroll 1
  for (int iv=0; iv<NI; iv++){
    // ---- dX(u) channels 1..8, pair layout ----
    for (int idx=tid; idx<5*BT*8; idx+=THR){
      int ui = idx >> 7; int r = idx & 127; int bb = r >> 3; int x8 = r & 7;
      float u = 0.25f*(float)ui;
      int gb = b0+bb;
      float m0 = m_ws[((size_t)iv    *Bsz + gb)*8 + x8];
      float m1 = m_ws[((size_t)(iv+1)*Bsz + gb)*8 + x8];
      float xd = a[((size_t)gb*Lsz + iv+1)*AD + x8] - a[((size_t)gb*Lsz + iv)*AD + x8];
      float cb = xd - (2.f*m0 + m1)*(1.f/6.f);
      float cc = 0.5f*m0;
      float cd = (m1 - m0)*(1.f/6.f);
      dXp[ui][bb>>1][x8*2 + (bb&1)] = cb + (2.f*cc)*u + (3.f*cd)*(u*u);
    }

    #pragma unroll 1
    for (int st=0; st<8; st++){
      const int ui = (st+1)>>1;      // {0,1,1,2,2,3,3,4}
      const int mode = st & 3;
      __syncthreads();               // zp, dXp ready; prev hp readers done

      // ---- GEMM1 packed: h[b-pair jg][j=2ol,2ol+1] ----
      {
        const int j0 = 2*ol;
        f32x2 acc0, acc1;
        PK_MUL_BCLO(acc0, b1pair, one11);
        PK_MUL_BCHI(acc1, b1pair, one11);
        const f32x4* zrow = (const f32x4*)&zp[jg][0];
        const f32x4* w0r = (const f32x4*)&W1t[j0][0];
        const f32x4* w1r = (const f32x4*)&W1t[j0+1][0];
        #pragma unroll
        for (int k16=0;k16<16;k16++){
          f32x4 zqA = zrow[2*k16], zqB = zrow[2*k16+1];
          f32x4 w0q = w0r[k16], w1q = w1r[k16];
          f32x2 w0l = LO2(w0q), w0h = HI2(w0q), w1l = LO2(w1q), w1h = HI2(w1q);
          f32x2 zA0 = LO2(zqA), zA1 = HI2(zqA), zB0 = LO2(zqB), zB1 = HI2(zqB);
          PK_FMA_BCLO(acc0, w0l, zA0); PK_FMA_BCHI(acc0, w0l, zA1);
          PK_FMA_BCLO(acc0, w0h, zB0); PK_FMA_BCHI(acc0, w0h, zB1);
          PK_FMA_BCLO(acc1, w1l, zA0); PK_FMA_BCHI(acc1, w1l, zA1);
          PK_FMA_BCLO(acc1, w1h, zB0); PK_FMA_BCHI(acc1, w1h, zB1);
        }
        f32x4 hv;
        hv.x = fmaxf(acc0.x, 0.f); hv.y = fmaxf(acc0.y, 0.f);
        hv.z = fmaxf(acc1.x, 0.f); hv.w = fmaxf(acc1.y, 0.f);
        *(f32x4*)&hp[jg][(ol>>3)*36 + (ol&7)*4] = hv;
      }
      __syncthreads();               // hp ready

      // ---- GEMM2: two half-batches of 4 b-pairs; per (bbat,ch) stage 8 j's AGPR->VGPR once ----
      f32x2 resKeep; resKeep.x = 0.f; resKeep.y = 0.f;
      #pragma unroll
      for (int bbat=0; bbat<2; bbat++){
        f32x2 dz[4];
        #pragma unroll
        for (int i=0;i<4;i++){ dz[i].x = 0.f; dz[i].y = 0.f; }
        #pragma unroll
        for (int ch=0; ch<2; ch++){
          // stage: 8 j's of W2 (32 pairs) + 4 c0 pairs, copied from AGPR exactly once
          f32x2 cw[8][4]; f32x2 cc[4];
          #pragma unroll
          for (int q=0;q<8;q++){
            cw[q][0]=wpk[ch*8+q][0]; cw[q][1]=wpk[ch*8+q][1];
            cw[q][2]=wpk[ch*8+q][2]; cw[q][3]=wpk[ch*8+q][3];
          }
          #pragma unroll
          for (int q=0;q<4;q++) cc[q]=wc0pk[ch*4+q];
          #pragma unroll
          for (int q=0;q<8;q++){
            asm volatile("" : "+v"(cw[q][0]), "+v"(cw[q][1]), "+v"(cw[q][2]), "+v"(cw[q][3]));
          }
          asm volatile("" : "+v"(cc[0]), "+v"(cc[1]), "+v"(cc[2]), "+v"(cc[3]));
          #pragma unroll
          for (int pi=0; pi<4; pi++){
            const int p = bbat*4 + pi;
            const f32x4* dxr = (const f32x4*)&dXp[ui][p][0];
            f32x4 d0=dxr[0], d1=dxr[1], d2=dxr[2], d3=dxr[3];
            f32x2 dx2[8] = {LO2(d0),HI2(d0),LO2(d1),HI2(d1),LO2(d2),HI2(d2),LO2(d3),HI2(d3)};
            const f32x4* hr = (const f32x4*)&hp[p][jg*36 + ch*16];
            #pragma unroll
            for (int q2=0;q2<4;q2++){
              f32x4 hq = hr[q2];
              f32x2 hl = LO2(hq), hh = HI2(hq);
              const int ja = 2*q2, jb = 2*q2+1;
              {
                f32x2 wd;
                PK_MUL_BCLO(wd, cw[ja][0], dx2[0]); PK_FMA_BCHI(wd, cw[ja][0], dx2[1]);
                PK_FMA_BCLO(wd, cw[ja][1], dx2[2]); PK_FMA_BCHI(wd, cw[ja][1], dx2[3]);
                PK_FMA_BCLO(wd, cw[ja][2], dx2[4]); PK_FMA_BCHI(wd, cw[ja][2], dx2[5]);
                PK_FMA_BCLO(wd, cw[ja][3], dx2[6]); PK_FMA_BCHI(wd, cw[ja][3], dx2[7]);
                PK_FMA_BCLO(wd, cc[q2], one11);
                PK_FMA(dz[pi], hl, wd);
              }
              {
                f32x2 wd;
                PK_MUL_BCLO(wd, cw[jb][0], dx2[0]); PK_FMA_BCHI(wd, cw[jb][0], dx2[1]);
                PK_FMA_BCLO(wd, cw[jb][1], dx2[2]); PK_FMA_BCHI(wd, cw[jb][1], dx2[3]);
                PK_FMA_BCLO(wd, cw[jb][2], dx2[4]); PK_FMA_BCHI(wd, cw[jb][2], dx2[5]);
                PK_FMA_BCLO(wd, cw[jb][3], dx2[6]); PK_FMA_BCHI(wd, cw[jb][3], dx2[7]);
                PK_FMA_BCHI(wd, cc[q2], one11);
                PK_FMA(dz[pi], hh, wd);
              }
            }
          }
        }
        // ---- butterfly dz[4] over jg lanes: xor1, xor2 -> pair (jg&3); xor4 joins j-halves ----
        const bool g1 = jg & 1;
        f32x2 n2[2];
        #pragma unroll
        for (int i=0;i<2;i++){
          f32x2 lo = dz[2*i], hi = dz[2*i+1];
          f32x2 send = g1 ? lo : hi;
          f32x2 recv; recv.x = DPP_XOR1(send.x); recv.y = DPP_XOR1(send.y);
          f32x2 keep = g1 ? hi : lo;
          PK_ADD(n2[i], keep, recv);
        }
        const bool g2 = jg & 2;
        f32x2 n1;
        {
          f32x2 lo = n2[0], hi = n2[1];
          f32x2 send = g2 ? lo : hi;
          f32x2 recv; recv.x = DPP_XOR2(send.x); recv.y = DPP_XOR2(send.y);
          f32x2 keep = g2 ? hi : lo;
          PK_ADD(n1, keep, recv);
        }
        f32x2 res;
        {
          f32x2 recv; recv.x = SWZ_XOR4(n1.x); recv.y = SWZ_XOR4(n1.y);
          PK_ADD(res, n1, recv);
        }
        if ((jg>>2) == bbat) resKeep = res;
      }

      // ---- bias: b2[ol]·dX[b-pair jg] (+ const t-channel), packed ----
      f32x2 bias2;
      {
        const f32x4* dxb = (const f32x4*)&dXp[ui][jg][0];
        f32x4 e0=dxb[0], e1=dxb[1], e2=dxb[2], e3=dxb[3];
        PK_MUL_BCLO(bias2, b2c0v, one11);
        PK_FMA_BCLO(bias2, b2p[0], LO2(e0)); PK_FMA_BCHI(bias2, b2p[0], HI2(e0));
        PK_FMA_BCLO(bias2, b2p[1], LO2(e1)); PK_FMA_BCHI(bias2, b2p[1], HI2(e1));
        PK_FMA_BCLO(bias2, b2p[2], LO2(e2)); PK_FMA_BCHI(bias2, b2p[2], HI2(e2));
        PK_FMA_BCLO(bias2, b2p[3], LO2(e3)); PK_FMA_BCHI(bias2, b2p[3], HI2(e3));
      }
      f32x2 dzm2; PK_ADD(dzm2, resKeep, bias2);
      const float dz0 = dzm2.x, dz1 = dzm2.y;

      // ---- RK4 bookkeeping (h = 0.5) ----
      float zn0, zn1;
      if (mode == 0){
        ka0 = dz0; ka1 = dz1;
        zn0 = fmaf(0.25f, dz0, zb0); zn1 = fmaf(0.25f, dz1, zb1);
      } else if (mode == 1){
        ka0 = fmaf(2.f, dz0, ka0); ka1 = fmaf(2.f, dz1, ka1);
        zn0 = fmaf(0.25f, dz0, zb0); zn1 = fmaf(0.25f, dz1, zb1);
      } else if (mode == 2){
        ka0 = fmaf(2.f, dz0, ka0); ka1 = fmaf(2.f, dz1, ka1);
        zn0 = fmaf(0.5f, dz0, zb0); zn1 = fmaf(0.5f, dz1, zb1);
      } else {
        ka0 += dz0; ka1 += dz1;
        zb0 = fmaf(0.5f/6.f, ka0, zb0); zb1 = fmaf(0.5f/6.f, ka1, zb1);
        zn0 = zb0; zn1 = zb1;
      }
      f32x2 zw; zw.x = zn0; zw.y = zn1;
      *(f32x2*)&zp[jg][2*ol] = zw;
    }

    __syncthreads();   // final z in zp; also fences dXp reads before next staging
    // ---- decode out[:, iv+1, :] ----
    {
      const int bb = tid >> 5; const int o = tid & 31; const int c = bb & 1;
      const float* zrow = &zp[bb>>1][0];
      float acc = dbs[o];
      #pragma unroll 16
      for (int k=0;k<LAT;k++) acc = fmaf(zrow[2*k+c], dWs[k][o], acc);
      out[((size_t)(b0+bb)*Lsz + (iv+1))*SD + o] = acc;
    }
  }
}

extern "C" void kernel_launch(void* const* d_in, const int* in_sizes, int n_in,
                              void* d_out, int out_size, void* d_ws, size_t ws_size,
                              hipStream_t stream){
  const float* s    = (const float*)d_in[0];
  const float* a    = (const float*)d_in[1];
  const float* t    = (const float*)d_in[2];
  const float* encW = (const float*)d_in[3];
  const float* encb = (const float*)d_in[4];
  const float* W1   = (const float*)d_in[5];
  const float* b1   = (const float*)d_in[6];
  const float* W2   = (const float*)d_in[7];
  const float* b2   = (const float*)d_in[8];
  const float* decW = (const float*)d_in[9];
  const float* decb = (const float*)d_in[10];
  float* out = (float*)d_out;
  float* ws  = (float*)d_ws;
  float* W2p8 = ws;                          // 65,536 floats
  float* W2c0 = ws + HID*LAT*8;              //  8,192 floats
  float* m_ws = ws + HID*LAT*9;              // 128*4096*8 floats (16.8MB)

  hipLaunchKernelGGL(repack_w2, dim3((HID*LAT*9+255)/256), dim3(256), 0, stream, W2, W2p8, W2c0);
  hipLaunchKernelGGL(spline_kernel, dim3(Bsz*8/256), dim3(256), 0, stream, a, m_ws);
  hipLaunchKernelGGL(cde_integrate, dim3(Bsz/BT), dim3(THR), 0, stream,
                     s,a,t,encW,encb,W1,b1,b2,decW,decb,W2p8,W2c0,m_ws,out);
}

// Round 11
// 9225.697 us; speedup vs baseline: 2.1043x; 2.1043x over previous
//
#include <hip/hip_runtime.h>

#define Bsz 4096
#define Lsz 128
#define NI  127
#define SD  32
#define AD  8
#define LAT 64
#define HID 128
#define BT  16
#define THR 1024

typedef float f32x2 __attribute__((ext_vector_type(2)));
typedef float f32x4 __attribute__((ext_vector_type(4)));

// ---------------- W2 repack: [j][l][9] -> W2p8 [j][l][8] (ch 1..8) + W2c0 [j][l] (ch 0) ----------------
__global__ __launch_bounds__(256) void repack_w2(const float* __restrict__ W2,
                                                 float* __restrict__ W2p8,
                                                 float* __restrict__ W2c0){
  int idx = blockIdx.x*256 + threadIdx.x;
  if (idx < HID*LAT*8){
    int x = idx & 7; int jl = idx >> 3; int l = jl & 63; int j = jl >> 6;
    W2p8[idx] = W2[(j*LAT + l)*9 + x + 1];
  } else if (idx < HID*LAT*9){
    int jl = idx - HID*LAT*8;
    W2c0[jl] = W2[(size_t)jl*9];
  }
}

// ---------------- Natural cubic spline: channels 1..8 (t-channel exactly linear) ----------------
__global__ __launch_bounds__(256) void spline_kernel(const float* __restrict__ a,
                                                     float* __restrict__ m_ws){
  __shared__ float cp_s[126];
  if (threadIdx.x == 0){
    float c = 0.25f; cp_s[0] = c;
    for (int i=1;i<126;i++){ c = 1.0f/(4.0f - c); cp_s[i] = c; }
  }
  __syncthreads();
  int tid = blockIdx.x*256 + threadIdx.x;   // tid = b*8 + c8
  int b = tid >> 3, c8 = tid & 7;
  float dp[126];
  const float* ab = a + (size_t)b*Lsz*AD + c8;
  float x0 = ab[0];
  float x1 = ab[AD];
  for (int i=0;i<126;i++){
    float x2 = ab[(size_t)(i+2)*AD];
    float rhs = 6.0f*(x2 - 2.0f*x1 + x0);
    dp[i] = (i==0)? rhs*0.25f : (rhs - dp[i-1])*cp_s[i];
    x0 = x1; x1 = x2;
  }
  m_ws[tid] = 0.0f;
  m_ws[((size_t)127*Bsz)*8 + tid] = 0.0f;
  float mn = 0.0f;
  for (int k=125;k>=0;k--){
    mn = dp[k] - cp_s[k]*mn;
    m_ws[((size_t)(k+1)*Bsz)*8 + tid] = mn;
  }
}

// ---- cross-lane helpers ----
#define DPP_XOR1(v) __int_as_float(__builtin_amdgcn_mov_dpp(__float_as_int(v), 0xB1, 0xF, 0xF, true))
#define DPP_XOR2(v) __int_as_float(__builtin_amdgcn_mov_dpp(__float_as_int(v), 0x4E, 0xF, 0xF, true))
#define SWZ_XOR4(v) __int_as_float(__builtin_amdgcn_ds_swizzle(__float_as_int(v), 0x101F))
#define SWZ_XOR8(v) __int_as_float(__builtin_amdgcn_ds_swizzle(__float_as_int(v), 0x201F))

// ---- packed fp32 (VOP3P); BCLO/BCHI broadcast src0's lo/hi half ----
#define PK_MUL_BCLO(d, w, x) asm("v_pk_mul_f32 %0, %1, %2 op_sel:[0,0] op_sel_hi:[0,1]" : "=v"(d) : "v"(w), "v"(x))
#define PK_MUL_BCHI(d, w, x) asm("v_pk_mul_f32 %0, %1, %2 op_sel:[1,0] op_sel_hi:[1,1]" : "=v"(d) : "v"(w), "v"(x))
#define PK_FMA_BCLO(acc, w, x) asm("v_pk_fma_f32 %0, %1, %2, %0 op_sel:[0,0,0] op_sel_hi:[0,1,1]" : "+v"(acc) : "v"(w), "v"(x))
#define PK_FMA_BCHI(acc, w, x) asm("v_pk_fma_f32 %0, %1, %2, %0 op_sel:[1,0,0] op_sel_hi:[1,1,1]" : "+v"(acc) : "v"(w), "v"(x))
#define PK_FMA(acc, a, b)      asm("v_pk_fma_f32 %0, %1, %2, %0" : "+v"(acc) : "v"(a), "v"(b))

#define LO2(v4) __builtin_shufflevector(v4, v4, 0, 1)
#define HI2(v4) __builtin_shufflevector(v4, v4, 2, 3)

// ---------------- Persistent RK4 integrator: 1024 thr, j-octet W2 (72 regs), pk + broadcast-LDS ----------------
__attribute__((amdgpu_waves_per_eu(4,4)))
__global__ __launch_bounds__(THR) void cde_integrate(
    const float* __restrict__ s, const float* __restrict__ a, const float* __restrict__ t,
    const float* __restrict__ encW, const float* __restrict__ encb,
    const float* __restrict__ W1, const float* __restrict__ b1,
    const float* __restrict__ b2, const float* __restrict__ decW, const float* __restrict__ decb,
    const float* __restrict__ W2p8, const float* __restrict__ W2c0, const float* __restrict__ m_ws,
    float* __restrict__ out)
{
  __shared__ float W1t[HID][LAT+4];   // [j][k], row 68
  __shared__ float hp[8][324];        // [b-pair][octet*20 + slot*4 + {je.c0,je.c1,jo.c0,jo.c1}]
  __shared__ float zp[8][132];        // [b-pair][l*2 + c]
  __shared__ float dXp[5][8][20];     // [u][b-pair][x8*2 + c]
  __shared__ float b2s[LAT][12];      // b2 row per l (9 used)
  __shared__ float dWs[LAT][SD];
  __shared__ float dbs[SD];

  const int tid = threadIdx.x;
  const int b0 = blockIdx.x * BT;
  // GEMM2 / RK4 ids
  const int ol = tid >> 4;    // 0..63 : l (also j-pair for GEMM1)
  const int jg = tid & 15;    // 0..15 : j-octet; butterfly delivers b-pair (jg&7)
  const int pown = jg & 7;
  // GEMM1 ids
  const int kh = (tid >> 3) & 1;  // k-half
  const int bp = tid & 7;         // b-pair

  // ---- LDS staging ----
  for (int i=tid;i<HID*LAT;i+=THR){ int j = i & (HID-1); int k = i >> 7; W1t[j][k] = W1[k*HID+j]; }
  for (int i=tid;i<LAT*SD;i+=THR)  ((float*)dWs)[i] = decW[i];
  for (int i=tid;i<LAT*12;i+=THR){ int l=i/12, x=i%12; b2s[l][x] = (x<9)? b2[l*9+x] : 0.f; }
  if (tid < SD) dbs[tid] = decb[tid];

  // ---- W2 j-octet -> registers (72 values) ----
  f32x2 wpk[8][4]; f32x2 wc0[4];
  {
    #pragma unroll
    for (int jj=0;jj<8;jj++){
      const f32x4* p4 = (const f32x4*)&W2p8[((size_t)(jg*8+jj)*LAT + ol)*8];
      f32x4 A = p4[0], B = p4[1];
      wpk[jj][0]=LO2(A); wpk[jj][1]=HI2(A); wpk[jj][2]=LO2(B); wpk[jj][3]=HI2(B);
    }
    #pragma unroll
    for (int q=0;q<4;q++){
      wc0[q].x = W2c0[(jg*8+2*q)*LAT + ol];
      wc0[q].y = W2c0[(jg*8+2*q+1)*LAT + ol];
    }
  }
  f32x2 b1pair; b1pair.x = b1[2*ol]; b1pair.y = b1[2*ol+1];
  f32x2 one11; one11.x = 1.f; one11.y = 1.f;

  // ---- encode z0: b = tid>>6 (0..15), l = tid&63 ----
  {
    const int b = tid >> 6;
    const int li = tid & 63;
    const float* sb = s + (size_t)(b0+b)*Lsz*SD;
    const float* ab = a + (size_t)(b0+b)*Lsz*AD;
    const float tv = t[(size_t)(b0+b)*Lsz];
    float acc = encb[li];
    #pragma unroll
    for (int k=0;k<SD;k++) acc = fmaf(sb[k], encW[k*LAT+li], acc);
    #pragma unroll
    for (int k=0;k<AD;k++) acc = fmaf(ab[k], encW[(SD+k)*LAT+li], acc);
    acc = fmaf(tv, encW[(SD+AD)*LAT+li], acc);
    zp[b>>1][li*2 + (b&1)] = acc;
  }
  __syncthreads();

  // ---- decode out[:,0,:] ----
  if (tid < BT*SD){
    const int bb = tid >> 5; const int o = tid & 31; const int c = bb & 1;
    const float* zrow = &zp[bb>>1][0];
    float acc = dbs[o];
    #pragma unroll 16
    for (int k=0;k<LAT;k++) acc = fmaf(zrow[2*k+c], dWs[k][o], acc);
    out[((size_t)(b0+bb)*Lsz + 0)*SD + o] = acc;
  }

  // ---- RK4 packed state: (l=ol, b-pair pown); lanes jg and jg+8 hold duplicates ----
  f32x2 zb, ka;
  { zb = *(const f32x2*)&zp[pown][2*ol]; ka.x = 0.f; ka.y = 0.f; }

  #pragma unroll 1
  for (int iv=0; iv<NI; iv++){
    // ---- dX(u) channels 1..8, pair layout ----
    if (tid < 5*BT*8){
      int ui = tid >> 7; int r = tid & 127; int bb = r >> 3; int x8 = r & 7;
      float u = 0.25f*(float)ui;
      int gb = b0+bb;
      float m0 = m_ws[((size_t)iv    *Bsz + gb)*8 + x8];
      float m1 = m_ws[((size_t)(iv+1)*Bsz + gb)*8 + x8];
      float xd = a[((size_t)gb*Lsz + iv+1)*AD + x8] - a[((size_t)gb*Lsz + iv)*AD + x8];
      float cb = xd - (2.f*m0 + m1)*(1.f/6.f);
      float cc = 0.5f*m0;
      float cd = (m1 - m0)*(1.f/6.f);
      dXp[ui][bb>>1][x8*2 + (bb&1)] = cb + (2.f*cc)*u + (3.f*cd)*(u*u);
    }

    #pragma unroll 1
    for (int st=0; st<8; st++){
      const int ui = (st+1)>>1;      // {0,1,1,2,2,3,3,4}
      const int mode = st & 3;
      __syncthreads();               // zp, dXp ready; prev hp readers done

      // ---- GEMM1 pk: thread (j-pair ol, kh, bp): half-k partial for 2 j x b-pair ----
      {
        f32x2 acc0, acc1;
        PK_MUL_BCLO(acc0, b1pair, one11);   // {b1[j0], b1[j0]}
        PK_MUL_BCHI(acc1, b1pair, one11);   // {b1[j1], b1[j1]}
        const f32x4* zr  = (const f32x4*)&zp[bp][kh*64];
        const f32x4* w0r = (const f32x4*)&W1t[2*ol][kh*32];
        const f32x4* w1r = (const f32x4*)&W1t[2*ol+1][kh*32];
        #pragma unroll
        for (int c4=0;c4<8;c4++){
          f32x4 w0q = w0r[c4], w1q = w1r[c4];
          f32x4 zA = zr[2*c4], zB = zr[2*c4+1];
          f32x2 w0l = LO2(w0q), w0h = HI2(w0q), w1l = LO2(w1q), w1h = HI2(w1q);
          f32x2 z0 = LO2(zA), z1 = HI2(zA), z2 = LO2(zB), z3 = HI2(zB);
          PK_FMA_BCLO(acc0, w0l, z0); PK_FMA_BCHI(acc0, w0l, z1);
          PK_FMA_BCLO(acc0, w0h, z2); PK_FMA_BCHI(acc0, w0h, z3);
          PK_FMA_BCLO(acc1, w1l, z0); PK_FMA_BCHI(acc1, w1l, z1);
          PK_FMA_BCLO(acc1, w1h, z2); PK_FMA_BCHI(acc1, w1h, z3);
        }
        // k-half reduce (partner = lane^8), both halves end with full sums
        acc0.x += SWZ_XOR8(acc0.x); acc0.y += SWZ_XOR8(acc0.y);
        acc1.x += SWZ_XOR8(acc1.x); acc1.y += SWZ_XOR8(acc1.y);
        if (kh == 0){
          f32x4 hv;
          hv.x = fmaxf(acc0.x,0.f); hv.y = fmaxf(acc0.y,0.f);
          hv.z = fmaxf(acc1.x,0.f); hv.w = fmaxf(acc1.y,0.f);
          *(f32x4*)&hp[bp][(ol>>2)*20 + (ol&3)*4] = hv;
        }
      }
      __syncthreads();               // hp ready

      // ---- GEMM2: two half-batches of 4 b-pairs; W2 register-resident ----
      f32x2 haA, haB;
      #pragma unroll
      for (int half=0; half<2; half++){
        f32x2 dzv[4];
        #pragma unroll
        for (int i=0;i<4;i++){ dzv[i].x = 0.f; dzv[i].y = 0.f; }
        #pragma unroll
        for (int pi=0; pi<4; pi++){
          const int p = half*4 + pi;
          const f32x4* dxr = (const f32x4*)&dXp[ui][p][0];
          f32x4 d0=dxr[0], d1=dxr[1], d2=dxr[2], d3=dxr[3];
          f32x2 dxp0=LO2(d0), dxp1=HI2(d0), dxp2=LO2(d1), dxp3=HI2(d1);
          f32x2 dxp4=LO2(d2), dxp5=HI2(d2), dxp6=LO2(d3), dxp7=HI2(d3);
          const f32x4* hr = (const f32x4*)&hp[p][jg*20];
          #pragma unroll
          for (int q=0;q<4;q++){
            f32x4 hq = hr[q];
            f32x2 hl = LO2(hq), hh = HI2(hq);
            const int ja = 2*q, jb = 2*q+1;
            {
              f32x2 wd;
              PK_MUL_BCLO(wd, wc0[q], one11);
              PK_FMA_BCLO(wd, wpk[ja][0], dxp0); PK_FMA_BCHI(wd, wpk[ja][0], dxp1);
              PK_FMA_BCLO(wd, wpk[ja][1], dxp2); PK_FMA_BCHI(wd, wpk[ja][1], dxp3);
              PK_FMA_BCLO(wd, wpk[ja][2], dxp4); PK_FMA_BCHI(wd, wpk[ja][2], dxp5);
              PK_FMA_BCLO(wd, wpk[ja][3], dxp6); PK_FMA_BCHI(wd, wpk[ja][3], dxp7);
              PK_FMA(dzv[pi], hl, wd);
            }
            {
              f32x2 wd;
              PK_MUL_BCHI(wd, wc0[q], one11);
              PK_FMA_BCLO(wd, wpk[jb][0], dxp0); PK_FMA_BCHI(wd, wpk[jb][0], dxp1);
              PK_FMA_BCLO(wd, wpk[jb][1], dxp2); PK_FMA_BCHI(wd, wpk[jb][1], dxp3);
              PK_FMA_BCLO(wd, wpk[jb][2], dxp4); PK_FMA_BCHI(wd, wpk[jb][2], dxp5);
              PK_FMA_BCLO(wd, wpk[jb][3], dxp6); PK_FMA_BCHI(wd, wpk[jb][3], dxp7);
              PK_FMA(dzv[pi], hh, wd);
            }
          }
        }
        // butterfly rounds 1 (lane^1) and 2 (lane^2): lane keeps local-p = 2*bit1 + bit0 of jg
        const bool g1 = jg & 1;
        f32x2 n2[2];
        #pragma unroll
        for (int i=0;i<2;i++){
          f32x2 keep = g1 ? dzv[2*i+1] : dzv[2*i];
          f32x2 send = g1 ? dzv[2*i]   : dzv[2*i+1];
          f32x2 recv; recv.x = DPP_XOR1(send.x); recv.y = DPP_XOR1(send.y);
          n2[i] = keep + recv;
        }
        const bool g2 = jg & 2;
        f32x2 keep = g2 ? n2[1] : n2[0];
        f32x2 send = g2 ? n2[0] : n2[1];
        f32x2 recv; recv.x = DPP_XOR2(send.x); recv.y = DPP_XOR2(send.y);
        f32x2 hres = keep + recv;
        if (half==0) haA = hres; else haB = hres;
      }
      // round 3 (lane^4): p = 4*bit2 + 2*bit1 + bit0 = jg&7
      {
        const bool g4 = jg & 4;
        f32x2 keep = g4 ? haB : haA;
        f32x2 send = g4 ? haA : haB;
        f32x2 recv; recv.x = SWZ_XOR4(send.x); recv.y = SWZ_XOR4(send.y);
        haA = keep + recv;
      }
      // round 4 (lane^8): join j-halves; lanes jg, jg+8 now both hold pair jg&7
      { f32x2 r8; r8.x = SWZ_XOR8(haA.x); r8.y = SWZ_XOR8(haA.y); haA = haA + r8; }

      // ---- bias: b2[ol] . dX[pair pown] (+ const t-channel) ----
      f32x2 bias2;
      {
        const f32x4* bq = (const f32x4*)&b2s[ol][0];
        f32x4 q0 = bq[0], q1 = bq[1], q2 = bq[2];
        const f32x4* dxr = (const f32x4*)&dXp[ui][pown][0];
        f32x4 d0=dxr[0], d1=dxr[1], d2=dxr[2], d3=dxr[3];
        f32x2 e0=LO2(d0), e1=HI2(d0), e2=LO2(d1), e3=HI2(d1);
        f32x2 e4=LO2(d2), e5=HI2(d2), e6=LO2(d3), e7=HI2(d3);
        f32x2 q0l = LO2(q0), q0h = HI2(q0), q1l = LO2(q1), q1h = HI2(q1), q2l = LO2(q2);
        PK_MUL_BCLO(bias2, q0l, one11);          // c0
        PK_FMA_BCHI(bias2, q0l, e0);             // ch1
        PK_FMA_BCLO(bias2, q0h, e1);             // ch2
        PK_FMA_BCHI(bias2, q0h, e2);             // ch3
        PK_FMA_BCLO(bias2, q1l, e3);             // ch4
        PK_FMA_BCHI(bias2, q1l, e4);             // ch5
        PK_FMA_BCLO(bias2, q1h, e5);             // ch6
        PK_FMA_BCHI(bias2, q1h, e6);             // ch7
        PK_FMA_BCLO(bias2, q2l, e7);             // ch8
      }
      f32x2 dzm = haA + bias2;

      // ---- RK4 bookkeeping (h = 0.5), packed ----
      f32x2 zn;
      if (mode == 0){
        ka = dzm;                    zn = zb + 0.25f*dzm;
      } else if (mode == 1){
        ka = ka + 2.f*dzm;           zn = zb + 0.25f*dzm;
      } else if (mode == 2){
        ka = ka + 2.f*dzm;           zn = zb + 0.5f*dzm;
      } else {
        ka = ka + dzm;               zb = zb + (0.5f/6.f)*ka;  zn = zb;
      }
      if (jg < 8) *(f32x2*)&zp[pown][2*ol] = zn;
      if (mode != 3){ /* zb unchanged */ }
    }

    __syncthreads();   // final z in zp; fences dXp before next interval's staging
    // ---- decode out[:, iv+1, :] ----
    if (tid < BT*SD){
      const int bb = tid >> 5; const int o = tid & 31; const int c = bb & 1;
      const float* zrow = &zp[bb>>1][0];
      float acc = dbs[o];
      #pragma unroll 16
      for (int k=0;k<LAT;k++) acc = fmaf(zrow[2*k+c], dWs[k][o], acc);
      out[((size_t)(b0+bb)*Lsz + (iv+1))*SD + o] = acc;
    }
  }
}

extern "C" void kernel_launch(void* const* d_in, const int* in_sizes, int n_in,
                              void* d_out, int out_size, void* d_ws, size_t ws_size,
                              hipStream_t stream){
  const float* s    = (const float*)d_in[0];
  const float* a    = (const float*)d_in[1];
  const float* t    = (const float*)d_in[2];
  const float* encW = (const float*)d_in[3];
  const float* encb = (const float*)d_in[4];
  const float* W1   = (const float*)d_in[5];
  const float* b1   = (const float*)d_in[6];
  const float* W2   = (const float*)d_in[7];
  const float* b2   = (const float*)d_in[8];
  const float* decW = (const float*)d_in[9];
  const float* decb = (const float*)d_in[10];
  float* out = (float*)d_out;
  float* ws  = (float*)d_ws;
  float* W2p8 = ws;                          // 65,536 floats
  float* W2c0 = ws + HID*LAT*8;              //  8,192 floats
  float* m_ws = ws + HID*LAT*9;              // 128*4096*8 floats (16.8MB)

  hipLaunchKernelGGL(repack_w2, dim3((HID*LAT*9+255)/256), dim3(256), 0, stream, W2, W2p8, W2c0);
  hipLaunchKernelGGL(spline_kernel, dim3(Bsz*8/256), dim3(256), 0, stream, a, m_ws);
  hipLaunchKernelGGL(cde_integrate, dim3(Bsz/BT), dim3(THR), 0, stream,
                     s,a,t,encW,encb,W1,b1,b2,decW,decb,W2p8,W2c0,m_ws,out);
}

// Round 12
// 8308.202 us; speedup vs baseline: 2.3367x; 1.1104x over previous
//
#include <hip/hip_runtime.h>

#define Bsz 4096
#define Lsz 128
#define NI  127
#define SD  32
#define AD  8
#define LAT 64
#define HID 128
#define BT  16
#define THR 512

typedef float f32x2 __attribute__((ext_vector_type(2)));
typedef float f32x4 __attribute__((ext_vector_type(4)));

// ---------------- W2 repack ----------------
// W2 [128][64][9] -> W2p8 [j][l][8] (channels 1..8) + W2c0 [j][l] (channel 0)
__global__ __launch_bounds__(256) void repack_w2(const float* __restrict__ W2,
                                                 float* __restrict__ W2p8,
                                                 float* __restrict__ W2c0){
  int idx = blockIdx.x*256 + threadIdx.x;
  if (idx < HID*LAT*8){
    int x = idx & 7; int jl = idx >> 3; int l = jl & 63; int j = jl >> 6;
    W2p8[idx] = W2[(j*LAT + l)*9 + x + 1];
  } else if (idx < HID*LAT*9){
    int jl = idx - HID*LAT*8;
    W2c0[jl] = W2[(size_t)jl*9];
  }
}

// ---------------- Natural cubic spline: channels 1..8 (t-channel exactly linear) ----------------
__global__ __launch_bounds__(256) void spline_kernel(const float* __restrict__ a,
                                                     float* __restrict__ m_ws){
  __shared__ float cp_s[126];
  if (threadIdx.x == 0){
    float c = 0.25f; cp_s[0] = c;
    for (int i=1;i<126;i++){ c = 1.0f/(4.0f - c); cp_s[i] = c; }
  }
  __syncthreads();
  int tid = blockIdx.x*256 + threadIdx.x;   // tid = b*8 + c8
  int b = tid >> 3, c8 = tid & 7;
  float dp[126];
  const float* ab = a + (size_t)b*Lsz*AD + c8;
  float x0 = ab[0];
  float x1 = ab[AD];
  for (int i=0;i<126;i++){
    float x2 = ab[(size_t)(i+2)*AD];
    float rhs = 6.0f*(x2 - 2.0f*x1 + x0);
    dp[i] = (i==0)? rhs*0.25f : (rhs - dp[i-1])*cp_s[i];
    x0 = x1; x1 = x2;
  }
  m_ws[tid] = 0.0f;
  m_ws[((size_t)127*Bsz)*8 + tid] = 0.0f;
  float mn = 0.0f;
  for (int k=125;k>=0;k--){
    mn = dp[k] - cp_s[k]*mn;
    m_ws[((size_t)(k+1)*Bsz)*8 + tid] = mn;
  }
}

// ---- cross-lane helpers (32-bit) ----
#define DPP_XOR1(v) __int_as_float(__builtin_amdgcn_mov_dpp(__float_as_int(v), 0xB1, 0xF, 0xF, true))
#define DPP_XOR2(v) __int_as_float(__builtin_amdgcn_mov_dpp(__float_as_int(v), 0x4E, 0xF, 0xF, true))
#define SWZ_XOR4(v) __int_as_float(__builtin_amdgcn_ds_swizzle(__float_as_int(v), 0x101F))

// ---- packed fp32 ops (VOP3P). BCLO/BCHI broadcast src0's lo/hi half to both result halves ----
#define PK_MUL_BCLO(d, w, x) asm("v_pk_mul_f32 %0, %1, %2 op_sel:[0,0] op_sel_hi:[0,1]" : "=v"(d) : "v"(w), "v"(x))
#define PK_MUL_BCHI(d, w, x) asm("v_pk_mul_f32 %0, %1, %2 op_sel:[1,0] op_sel_hi:[1,1]" : "=v"(d) : "v"(w), "v"(x))
#define PK_FMA_BCLO(acc, w, x) asm("v_pk_fma_f32 %0, %1, %2, %0 op_sel:[0,0,0] op_sel_hi:[0,1,1]" : "+v"(acc) : "v"(w), "v"(x))
#define PK_FMA_BCHI(acc, w, x) asm("v_pk_fma_f32 %0, %1, %2, %0 op_sel:[1,0,0] op_sel_hi:[1,1,1]" : "+v"(acc) : "v"(w), "v"(x))
#define PK_FMA(acc, a, b)      asm("v_pk_fma_f32 %0, %1, %2, %0" : "+v"(acc) : "v"(a), "v"(b))
#define PK_ADD(d, a, b)        asm("v_pk_add_f32 %0, %1, %2" : "=v"(d) : "v"(a), "v"(b))

#define LO2(v4) __builtin_shufflevector(v4, v4, 0, 1)
#define HI2(v4) __builtin_shufflevector(v4, v4, 2, 3)

// ---------------- Persistent RK4 integrator: 512 thr, min 2 waves/EU -> 256-VGPR budget ----------------
__global__ __launch_bounds__(THR, 2) void cde_integrate(
    const float* __restrict__ s, const float* __restrict__ a, const float* __restrict__ t,
    const float* __restrict__ encW, const float* __restrict__ encb,
    const float* __restrict__ W1, const float* __restrict__ b1,
    const float* __restrict__ b2, const float* __restrict__ decW, const float* __restrict__ decb,
    const float* __restrict__ W2p8, const float* __restrict__ W2c0, const float* __restrict__ m_ws,
    float* __restrict__ out)
{
  __shared__ float W1t[HID][LAT+4];   // [j][k], row 68 (272B, 16B-aligned)
  __shared__ float hp[8][292];        // [b-pair][jblock*36 + chunk*4 + {e0,o0,e1,o1}]
  __shared__ float zp[8][132];        // [b-pair][l*2 + c]
  __shared__ float dXp[5][8][20];     // [u][b-pair][x8*2 + c]
  __shared__ float dWs[LAT][SD];
  __shared__ float dbs[SD];

  const int tid = threadIdx.x;
  const int b0 = blockIdx.x * BT;
  const int ol = tid >> 3;   // 0..63 : latent l (GEMM2/RK4), j-pair (GEMM1)
  const int jg = tid & 7;    // 0..7  : j-group (GEMM2), b-pair (GEMM1/RK4)

  // ---- LDS weight staging ----
  for (int i=tid;i<HID*LAT;i+=THR){ int j = i & (HID-1); int k = i >> 7; W1t[j][k] = W1[k*HID+j]; }
  for (int i=tid;i<LAT*SD;i+=THR)  ((float*)dWs)[i] = decW[i];
  if (tid < SD) dbs[tid] = decb[tid];

  // ---- W2 -> arch VGPRs as channel pairs; j set = jg*16..+15 at column ol ----
  f32x2 wpk[16][4]; f32x2 wc0pk[8];
  {
    #pragma unroll
    for (int jj=0;jj<16;jj++){
      const f32x2* p2 = (const f32x2*)&W2p8[((size_t)(jg*16+jj)*LAT + ol)*8];
      wpk[jj][0]=p2[0]; wpk[jj][1]=p2[1]; wpk[jj][2]=p2[2]; wpk[jj][3]=p2[3];
    }
    #pragma unroll
    for (int q=0;q<8;q++){
      wc0pk[q].x = W2c0[(jg*16+2*q)*LAT + ol];
      wc0pk[q].y = W2c0[(jg*16+2*q+1)*LAT + ol];
    }
  }
  f32x2 b2p[4]; f32x2 b2c0v; f32x2 b1pair; f32x2 one11; one11.x = 1.f; one11.y = 1.f;
  {
    const float* bp = b2 + ol*9;
    b2c0v.x = bp[0]; b2c0v.y = 0.f;
    b2p[0].x = bp[1]; b2p[0].y = bp[2];
    b2p[1].x = bp[3]; b2p[1].y = bp[4];
    b2p[2].x = bp[5]; b2p[2].y = bp[6];
    b2p[3].x = bp[7]; b2p[3].y = bp[8];
    b1pair.x = b1[2*ol]; b1pair.y = b1[2*ol+1];
  }

  // ---- encode z0: thread handles (b, b+8) for b = tid>>6, l = tid&63 ----
  {
    const int bb8 = tid >> 6;        // 0..7
    const int li = tid & 63;
    #pragma unroll
    for (int h=0; h<2; h++){
      const int b = bb8 + 8*h;
      const float* sb = s + (size_t)(b0+b)*Lsz*SD;
      const float* ab = a + (size_t)(b0+b)*Lsz*AD;
      const float tv = t[(size_t)(b0+b)*Lsz];
      float acc = encb[li];
      #pragma unroll
      for (int k=0;k<SD;k++) acc = fmaf(sb[k], encW[k*LAT+li], acc);
      #pragma unroll
      for (int k=0;k<AD;k++) acc = fmaf(ab[k], encW[(SD+k)*LAT+li], acc);
      acc = fmaf(tv, encW[(SD+AD)*LAT+li], acc);
      zp[b>>1][li*2 + (b&1)] = acc;
    }
  }
  __syncthreads();

  // ---- decode out[:,0,:] ----
  {
    const int bb = tid >> 5; const int o = tid & 31; const int c = bb & 1;
    const float* zrow = &zp[bb>>1][0];
    float acc = dbs[o];
    #pragma unroll 16
    for (int k=0;k<LAT;k++) acc = fmaf(zrow[2*k+c], dWs[k][o], acc);
    out[((size_t)(b0+bb)*Lsz + 0)*SD + o] = acc;
  }

  // ---- RK4 packed state: thread owns l=ol, b-pair jg ----
  float zb0, zb1, ka0 = 0.f, ka1 = 0.f;
  { f32x2 zr = *(const f32x2*)&zp[jg][2*ol]; zb0 = zr.x; zb1 = zr.y; }

  #pragma unroll 1
  for (int iv=0; iv<NI; iv++){
    // ---- dX(u) channels 1..8, pair layout ----
    for (int idx=tid; idx<5*BT*8; idx+=THR){
      int ui = idx >> 7; int r = idx & 127; int bb = r >> 3; int x8 = r & 7;
      float u = 0.25f*(float)ui;
      int gb = b0+bb;
      float m0 = m_ws[((size_t)iv    *Bsz + gb)*8 + x8];
      float m1 = m_ws[((size_t)(iv+1)*Bsz + gb)*8 + x8];
      float xd = a[((size_t)gb*Lsz + iv+1)*AD + x8] - a[((size_t)gb*Lsz + iv)*AD + x8];
      float cb = xd - (2.f*m0 + m1)*(1.f/6.f);
      float cc = 0.5f*m0;
      float cd = (m1 - m0)*(1.f/6.f);
      dXp[ui][bb>>1][x8*2 + (bb&1)] = cb + (2.f*cc)*u + (3.f*cd)*(u*u);
    }

    #pragma unroll 1
    for (int st=0; st<8; st++){
      const int ui = (st+1)>>1;      // {0,1,1,2,2,3,3,4}
      const int mode = st & 3;
      __syncthreads();               // zp, dXp ready; prev hp readers done

      // ---- GEMM1 packed: h[b-pair jg][j=2ol,2ol+1] ----
      {
        const int j0 = 2*ol;
        f32x2 acc0, acc1;
        PK_MUL_BCLO(acc0, b1pair, one11);
        PK_MUL_BCHI(acc1, b1pair, one11);
        const f32x4* zrow = (const f32x4*)&zp[jg][0];
        const f32x4* w0r = (const f32x4*)&W1t[j0][0];
        const f32x4* w1r = (const f32x4*)&W1t[j0+1][0];
        #pragma unroll
        for (int k16=0;k16<16;k16++){
          f32x4 zqA = zrow[2*k16], zqB = zrow[2*k16+1];
          f32x4 w0q = w0r[k16], w1q = w1r[k16];
          f32x2 w0l = LO2(w0q), w0h = HI2(w0q), w1l = LO2(w1q), w1h = HI2(w1q);
          f32x2 zA0 = LO2(zqA), zA1 = HI2(zqA), zB0 = LO2(zqB), zB1 = HI2(zqB);
          PK_FMA_BCLO(acc0, w0l, zA0); PK_FMA_BCHI(acc0, w0l, zA1);
          PK_FMA_BCLO(acc0, w0h, zB0); PK_FMA_BCHI(acc0, w0h, zB1);
          PK_FMA_BCLO(acc1, w1l, zA0); PK_FMA_BCHI(acc1, w1l, zA1);
          PK_FMA_BCLO(acc1, w1h, zB0); PK_FMA_BCHI(acc1, w1h, zB1);
        }
        f32x4 hv;
        hv.x = fmaxf(acc0.x, 0.f); hv.y = fmaxf(acc0.y, 0.f);
        hv.z = fmaxf(acc1.x, 0.f); hv.w = fmaxf(acc1.y, 0.f);
        *(f32x4*)&hp[jg][(ol>>3)*36 + (ol&7)*4] = hv;
      }
      __syncthreads();               // hp ready

      // ---- pin W2 pairs into arch VGPRs for this stage (cheap if already resident) ----
      #pragma unroll
      for (int jj=0;jj<16;jj+=2){
        asm volatile("" : "+v"(wpk[jj][0]), "+v"(wpk[jj][1]), "+v"(wpk[jj][2]), "+v"(wpk[jj][3]),
                          "+v"(wpk[jj+1][0]), "+v"(wpk[jj+1][1]), "+v"(wpk[jj+1][2]), "+v"(wpk[jj+1][3]));
      }
      asm volatile("" : "+v"(wc0pk[0]), "+v"(wc0pk[1]), "+v"(wc0pk[2]), "+v"(wc0pk[3]),
                        "+v"(wc0pk[4]), "+v"(wc0pk[5]), "+v"(wc0pk[6]), "+v"(wc0pk[7]));

      // ---- GEMM2 packed over b-pairs ----
      f32x2 dz[8];
      #pragma unroll
      for (int p=0;p<8;p++){ dz[p].x = 0.f; dz[p].y = 0.f; }
      #pragma unroll
      for (int p=0;p<8;p++){
        const f32x4* dxr = (const f32x4*)&dXp[ui][p][0];
        f32x4 d0=dxr[0], d1=dxr[1], d2=dxr[2], d3=dxr[3];
        f32x2 dx2[8] = {LO2(d0),HI2(d0),LO2(d1),HI2(d1),LO2(d2),HI2(d2),LO2(d3),HI2(d3)};
        const f32x4* hr = (const f32x4*)&hp[p][jg*36];
        #pragma unroll
        for (int jj2=0;jj2<8;jj2++){
          f32x4 hq = hr[jj2];
          f32x2 hl = LO2(hq), hh = HI2(hq);
          {
            f32x2 wd;
            PK_MUL_BCLO(wd, wpk[2*jj2][0], dx2[0]); PK_FMA_BCHI(wd, wpk[2*jj2][0], dx2[1]);
            PK_FMA_BCLO(wd, wpk[2*jj2][1], dx2[2]); PK_FMA_BCHI(wd, wpk[2*jj2][1], dx2[3]);
            PK_FMA_BCLO(wd, wpk[2*jj2][2], dx2[4]); PK_FMA_BCHI(wd, wpk[2*jj2][2], dx2[5]);
            PK_FMA_BCLO(wd, wpk[2*jj2][3], dx2[6]); PK_FMA_BCHI(wd, wpk[2*jj2][3], dx2[7]);
            PK_FMA_BCLO(wd, wc0pk[jj2], one11);
            PK_FMA(dz[p], hl, wd);
          }
          {
            f32x2 wd;
            PK_MUL_BCLO(wd, wpk[2*jj2+1][0], dx2[0]); PK_FMA_BCHI(wd, wpk[2*jj2+1][0], dx2[1]);
            PK_FMA_BCLO(wd, wpk[2*jj2+1][1], dx2[2]); PK_FMA_BCHI(wd, wpk[2*jj2+1][1], dx2[3]);
            PK_FMA_BCLO(wd, wpk[2*jj2+1][2], dx2[4]); PK_FMA_BCHI(wd, wpk[2*jj2+1][2], dx2[5]);
            PK_FMA_BCLO(wd, wpk[2*jj2+1][3], dx2[6]); PK_FMA_BCHI(wd, wpk[2*jj2+1][3], dx2[7]);
            PK_FMA_BCHI(wd, wc0pk[jj2], one11);
            PK_FMA(dz[p], hh, wd);
          }
        }
      }

      // ---- butterfly over 8 jg lanes: 3 rounds -> lane jg owns pair jg ----
      const bool g1 = jg & 1;
      f32x2 n4[4];
      #pragma unroll
      for (int i=0;i<4;i++){
        f32x2 lo = dz[2*i], hi = dz[2*i+1];
        f32x2 send = g1 ? lo : hi;
        f32x2 recv; recv.x = DPP_XOR1(send.x); recv.y = DPP_XOR1(send.y);
        f32x2 keep = g1 ? hi : lo;
        PK_ADD(n4[i], keep, recv);
      }
      const bool g2 = jg & 2;
      f32x2 n2[2];
      #pragma unroll
      for (int i=0;i<2;i++){
        f32x2 lo = n4[2*i], hi = n4[2*i+1];
        f32x2 send = g2 ? lo : hi;
        f32x2 recv; recv.x = DPP_XOR2(send.x); recv.y = DPP_XOR2(send.y);
        f32x2 keep = g2 ? hi : lo;
        PK_ADD(n2[i], keep, recv);
      }
      const bool g4 = jg & 4;
      f32x2 res;
      {
        f32x2 lo = n2[0], hi = n2[1];
        f32x2 send = g4 ? lo : hi;
        f32x2 recv; recv.x = SWZ_XOR4(send.x); recv.y = SWZ_XOR4(send.y);
        f32x2 keep = g4 ? hi : lo;
        PK_ADD(res, keep, recv);
      }

      // ---- bias: b2[ol]·dX[b-pair jg] (+ const t-channel), packed ----
      f32x2 bias2;
      {
        const f32x4* dxb = (const f32x4*)&dXp[ui][jg][0];
        f32x4 e0=dxb[0], e1=dxb[1], e2=dxb[2], e3=dxb[3];
        PK_MUL_BCLO(bias2, b2c0v, one11);
        PK_FMA_BCLO(bias2, b2p[0], LO2(e0)); PK_FMA_BCHI(bias2, b2p[0], HI2(e0));
        PK_FMA_BCLO(bias2, b2p[1], LO2(e1)); PK_FMA_BCHI(bias2, b2p[1], HI2(e1));
        PK_FMA_BCLO(bias2, b2p[2], LO2(e2)); PK_FMA_BCHI(bias2, b2p[2], HI2(e2));
        PK_FMA_BCLO(bias2, b2p[3], LO2(e3)); PK_FMA_BCHI(bias2, b2p[3], HI2(e3));
      }
      f32x2 dzm2; PK_ADD(dzm2, res, bias2);
      const float dz0 = dzm2.x, dz1 = dzm2.y;

      // ---- RK4 bookkeeping (h = 0.5), two scalar states ----
      float zn0, zn1;
      if (mode == 0){
        ka0 = dz0; ka1 = dz1;
        zn0 = fmaf(0.25f, dz0, zb0); zn1 = fmaf(0.25f, dz1, zb1);
      } else if (mode == 1){
        ka0 = fmaf(2.f, dz0, ka0); ka1 = fmaf(2.f, dz1, ka1);
        zn0 = fmaf(0.25f, dz0, zb0); zn1 = fmaf(0.25f, dz1, zb1);
      } else if (mode == 2){
        ka0 = fmaf(2.f, dz0, ka0); ka1 = fmaf(2.f, dz1, ka1);
        zn0 = fmaf(0.5f, dz0, zb0); zn1 = fmaf(0.5f, dz1, zb1);
      } else {
        ka0 += dz0; ka1 += dz1;
        zb0 = fmaf(0.5f/6.f, ka0, zb0); zb1 = fmaf(0.5f/6.f, ka1, zb1);
        zn0 = zb0; zn1 = zb1;
      }
      f32x2 zw; zw.x = zn0; zw.y = zn1;
      *(f32x2*)&zp[jg][2*ol] = zw;
    }

    __syncthreads();   // final z in zp; also fences dXp reads before next staging
    // ---- decode out[:, iv+1, :] ----
    {
      const int bb = tid >> 5; const int o = tid & 31; const int c = bb & 1;
      const float* zrow = &zp[bb>>1][0];
      float acc = dbs[o];
      #pragma unroll 16
      for (int k=0;k<LAT;k++) acc = fmaf(zrow[2*k+c], dWs[k][o], acc);
      out[((size_t)(b0+bb)*Lsz + (iv+1))*SD + o] = acc;
    }
  }
}

extern "C" void kernel_launch(void* const* d_in, const int* in_sizes, int n_in,
                              void* d_out, int out_size, void* d_ws, size_t ws_size,
                              hipStream_t stream){
  const float* s    = (const float*)d_in[0];
  const float* a    = (const float*)d_in[1];
  const float* t    = (const float*)d_in[2];
  const float* encW = (const float*)d_in[3];
  const float* encb = (const float*)d_in[4];
  const float* W1   = (const float*)d_in[5];
  const float* b1   = (const float*)d_in[6];
  const float* W2   = (const float*)d_in[7];
  const float* b2   = (const float*)d_in[8];
  const float* decW = (const float*)d_in[9];
  const float* decb = (const float*)d_in[10];
  float* out = (float*)d_out;
  float* ws  = (float*)d_ws;
  float* W2p8 = ws;                          // 65,536 floats
  float* W2c0 = ws + HID*LAT*8;              //  8,192 floats
  float* m_ws = ws + HID*LAT*9;              // 128*4096*8 floats (16.8MB)

  hipLaunchKernelGGL(repack_w2, dim3((HID*LAT*9+255)/256), dim3(256), 0, stream, W2, W2p8, W2c0);
  hipLaunchKernelGGL(spline_kernel, dim3(Bsz*8/256), dim3(256), 0, stream, a, m_ws);
  hipLaunchKernelGGL(cde_integrate, dim3(Bsz/BT), dim3(THR), 0, stream,
                     s,a,t,encW,encb,W1,b1,b2,decW,decb,W2p8,W2c0,m_ws,out);
}